// Round 7
// baseline (671.224 us; speedup 1.0000x reference)
//
#include <hip/hip_runtime.h>
#include <hip/hip_bf16.h>

#define S_LEN 127
#define NB    32
#define HDIM  256
#define DH    64
#define SCALE_F 0.125f
#define NBLK  1024
#define NTHR  256

typedef __bf16 bf16x8 __attribute__((ext_vector_type(8)));
typedef __bf16 bf16x4 __attribute__((ext_vector_type(4)));
typedef float  f32x4  __attribute__((ext_vector_type(4)));

#define NTOK  4064                 // NB * S_LEN
#define NQKV4 260096               // NTOK*HDIM/4 float4 groups per q/k/v
#define NW4   16384                // 256*256/4 float4 groups per W
#define TOT4  (3 * NQKV4 + 4 * NW4)  // 845824

// ---------------------------------------------------------------------------
// Grid barrier, load-polling (fixes R3's RMW-poll storm).
// Arrival: one ACQ_REL fetch_add per block. Poll: agent-scope ACQUIRE *load*
// (no RMW -> no serialization against arrivals), s_sleep backoff.
// __threadfence() = agent fence (L2 wb/inv) for cross-XCD visibility.
// Safe: __launch_bounds__(256,4) => VGPR<=128 => 4 blocks/CU => all 1024
// blocks co-resident (R3 demonstrated co-residency at this shape).
// ---------------------------------------------------------------------------
__device__ __forceinline__ void grid_barrier(unsigned* cnt, unsigned target) {
  __syncthreads();                 // drain all waves' stores (vmcnt 0)
  if (threadIdx.x == 0) {
    __threadfence();               // release: writeback local L2
    __hip_atomic_fetch_add(cnt, 1u, __ATOMIC_ACQ_REL, __HIP_MEMORY_SCOPE_AGENT);
    while (__hip_atomic_load(cnt, __ATOMIC_ACQUIRE, __HIP_MEMORY_SCOPE_AGENT) < target)
      __builtin_amdgcn_s_sleep(4);
    __threadfence();               // acquire: invalidate local L2
  }
  __syncthreads();
}

// ---------------------------------------------------------------------------
// Per-wave 32x32 tile, pure-bf16 operands (R5/R6-proven).
// ---------------------------------------------------------------------------
__device__ __forceinline__ void gemm_tile32_bf16(
    const __bf16* __restrict__ A, const __bf16* __restrict__ W,
    const float* __restrict__ bias, float* __restrict__ out,
    int row0, int col0)
{
  const int lane = threadIdx.x & 63;
  const int r  = lane & 15;
  const int ks = (lane >> 4) << 3;
  const __bf16* Ab = A + (size_t)(row0 + r) * HDIM + ks;
  const __bf16* Wb = W + (size_t)(col0 + r) * HDIM + ks;
  f32x4 acc[2][2] = {};

  bf16x8 ca[2], cw[2];
  ca[0] = *(const bf16x8*)Ab;
  ca[1] = *(const bf16x8*)(Ab + (size_t)16 * HDIM);
  cw[0] = *(const bf16x8*)Wb;
  cw[1] = *(const bf16x8*)(Wb + (size_t)16 * HDIM);
#pragma unroll
  for (int kb = 0; kb < 8; ++kb) {
    bf16x8 na[2], nw[2];
    if (kb < 7) {
      const int off = (kb + 1) * 32;
      na[0] = *(const bf16x8*)(Ab + off);
      na[1] = *(const bf16x8*)(Ab + (size_t)16 * HDIM + off);
      nw[0] = *(const bf16x8*)(Wb + off);
      nw[1] = *(const bf16x8*)(Wb + (size_t)16 * HDIM + off);
    }
#pragma unroll
    for (int mi = 0; mi < 2; ++mi)
#pragma unroll
      for (int ni = 0; ni < 2; ++ni)
        acc[mi][ni] = __builtin_amdgcn_mfma_f32_16x16x32_bf16(
            ca[mi], cw[ni], acc[mi][ni], 0, 0, 0);
    if (kb < 7) {
      ca[0] = na[0]; ca[1] = na[1];
      cw[0] = nw[0]; cw[1] = nw[1];
    }
  }
  const int crow = (lane >> 4) * 4;
  const int ccol = lane & 15;
#pragma unroll
  for (int mi = 0; mi < 2; ++mi)
#pragma unroll
    for (int ni = 0; ni < 2; ++ni) {
      const int oc = col0 + ni * 16 + ccol;
      const float bv = bias[oc];
#pragma unroll
      for (int rg = 0; rg < 4; ++rg)
        out[(size_t)(row0 + mi * 16 + crow + rg) * HDIM + oc] = acc[mi][ni][rg] + bv;
    }
}

// ---------------------------------------------------------------------------
// Fused pipeline: convert -> B -> qkv gemm -> B -> attn(x4 items) -> B -> o gemm
// ---------------------------------------------------------------------------
__global__ __launch_bounds__(256, 4) void fused_mha(
    const float* __restrict__ query, const float* __restrict__ key,
    const float* __restrict__ value, const int* __restrict__ graph,
    const float* __restrict__ ekt, const float* __restrict__ evt,
    const float* __restrict__ eqt,
    const float* __restrict__ Wq, const float* __restrict__ bq,
    const float* __restrict__ Wk, const float* __restrict__ bk,
    const float* __restrict__ Wv, const float* __restrict__ bv,
    const float* __restrict__ Wo, const float* __restrict__ bo,
    float* __restrict__ qp, float* __restrict__ kp, float* __restrict__ vp,
    __bf16* __restrict__ qb, __bf16* __restrict__ kb, __bf16* __restrict__ vb,
    __bf16* __restrict__ xpb,
    __bf16* __restrict__ Wqb, __bf16* __restrict__ Wkb,
    __bf16* __restrict__ Wvb, __bf16* __restrict__ Wob,
    float* __restrict__ out, unsigned* __restrict__ cnt)
{
  const int w  = threadIdx.x >> 6;
  const int l  = threadIdx.x & 63;
  const int ll = l & 15;
  const int g  = l >> 4;

  __shared__ int   s_list[S_LEN];
  __shared__ float s_attn[4][S_LEN];
  __shared__ int   s_cnt[2];

  // ============ Phase 0: f32 -> bf16 conversion (grid-strided) ============
  {
    const size_t stride = (size_t)NBLK * NTHR;
    for (size_t t0 = (size_t)blockIdx.x * NTHR + threadIdx.x; t0 < TOT4; t0 += stride) {
      size_t t = t0;
      const float* src; __bf16* dst;
      if (t < NQKV4)                 { src = query; dst = qb;  }
      else if ((t -= NQKV4) < NQKV4) { src = key;   dst = kb;  }
      else if ((t -= NQKV4) < NQKV4) { src = value; dst = vb;  }
      else if ((t -= NQKV4) < NW4)   { src = Wq;    dst = Wqb; }
      else if ((t -= NW4) < NW4)     { src = Wk;    dst = Wkb; }
      else if ((t -= NW4) < NW4)     { src = Wv;    dst = Wvb; }
      else { t -= NW4;                 src = Wo;    dst = Wob; }
      const float4 x = ((const float4*)src)[t];
      bf16x4 rr;
      rr[0] = (__bf16)x.x; rr[1] = (__bf16)x.y;
      rr[2] = (__bf16)x.z; rr[3] = (__bf16)x.w;
      ((bf16x4*)dst)[t] = rr;
    }
  }
  grid_barrier(cnt + 0, NBLK);

  // ============ Phase 1: q/k/v projections (3048 tile-waves) ==============
  {
    const int gw = blockIdx.x * 4 + w;
    if (gw < 3 * 1016) {
      const int pj = gw / 1016;
      const int t  = gw % 1016;
      const __bf16* A; const __bf16* W; const float* bias; float* o;
      if (pj == 0)      { A = qb; W = Wqb; bias = bq; o = qp; }
      else if (pj == 1) { A = kb; W = Wkb; bias = bk; o = kp; }
      else              { A = vb; W = Wvb; bias = bv; o = vp; }
      gemm_tile32_bf16(A, W, bias, o, (t % 127) * 32, (t / 127) * 32);
    }
  }
  grid_barrier(cnt + 16, NBLK);

  // ============ Phase 2: sparse attention (4064 items, <=4 per block) =====
  for (int item = blockIdx.x; item < NB * S_LEN; item += NBLK) {
    __syncthreads();   // protect LDS reuse across items
    int b, q;
    if (item < 96) { b = item / 3; q = item % 3; }
    else { const int rr2 = item - 96; b = rr2 / 124; q = 3 + rr2 % 124; }

    bool valid = false;
    const int k0 = w * 64 + l;
    if (w < 2 && k0 < S_LEN) {
      const int gr = graph[((size_t)b * S_LEN + q) * S_LEN + k0];
      bool keep;
      if (q < 3 || k0 < 3) keep = true;
      else {
        const int blk = 3 + 2 * ((q - 3) >> 1);
        keep = (k0 >= blk) & (k0 < blk + 2);
      }
      valid = (gr != 0) && keep;
    }
    const unsigned long long bal = __ballot(valid);
    if (w < 2 && l == 0) s_cnt[w] = (int)__popcll(bal);
    __syncthreads();
    int n = s_cnt[0] + s_cnt[1];
    if (valid) {
      const int pos = (int)__popcll(bal & ((1ull << l) - 1ull)) + (w ? s_cnt[0] : 0);
      s_list[pos] = k0;
    }
    __syncthreads();

    if (n == 0) {
      if (threadIdx.x < S_LEN) {
        s_list[threadIdx.x] = threadIdx.x;
        const float u = 1.0f / 127.0f;
        s_attn[0][threadIdx.x] = u; s_attn[1][threadIdx.x] = u;
        s_attn[2][threadIdx.x] = u; s_attn[3][threadIdx.x] = u;
      }
      n = S_LEN;
    } else {
      const float* qrow = qp + ((size_t)b * S_LEN + q) * HDIM;
      float4 q4[4];
#pragma unroll
      for (int h = 0; h < 4; ++h)
        q4[h] = *(const float4*)(qrow + h * 64 + ll * 4);
      const float* eqb2 = eqt + ((size_t)b * S_LEN * S_LEN + q) * DH;
      const float* ekb2 = ekt + ((size_t)(b * S_LEN + q)) * S_LEN * DH;
      const float* kpb  = kp + (size_t)b * S_LEN * HDIM;

      for (int i0 = 0; i0 < n; i0 += 16) {
        const int i = i0 + w * 4 + g;
        float p0 = 0.f, p1 = 0.f, p2 = 0.f, p3 = 0.f;
        if (i < n) {
          const int kk = s_list[i];
          const float4 eq4 = *(const float4*)(eqb2 + (size_t)kk * (S_LEN * DH) + ll * 4);
          const float4 ek4 = *(const float4*)(ekb2 + kk * DH + ll * 4);
          const float* kr = kpb + (size_t)kk * HDIM + ll * 4;
          const float4 kh0 = *(const float4*)(kr);
          const float4 kh1 = *(const float4*)(kr + 64);
          const float4 kh2 = *(const float4*)(kr + 128);
          const float4 kh3 = *(const float4*)(kr + 192);
          const float tx = ek4.x, ty = ek4.y, tz = ek4.z, tw = ek4.w;
          p0 = (q4[0].x+eq4.x)*(kh0.x+tx) + (q4[0].y+eq4.y)*(kh0.y+ty)
             + (q4[0].z+eq4.z)*(kh0.z+tz) + (q4[0].w+eq4.w)*(kh0.w+tw);
          p1 = (q4[1].x+eq4.x)*(kh1.x+tx) + (q4[1].y+eq4.y)*(kh1.y+ty)
             + (q4[1].z+eq4.z)*(kh1.z+tz) + (q4[1].w+eq4.w)*(kh1.w+tw);
          p2 = (q4[2].x+eq4.x)*(kh2.x+tx) + (q4[2].y+eq4.y)*(kh2.y+ty)
             + (q4[2].z+eq4.z)*(kh2.z+tz) + (q4[2].w+eq4.w)*(kh2.w+tw);
          p3 = (q4[3].x+eq4.x)*(kh3.x+tx) + (q4[3].y+eq4.y)*(kh3.y+ty)
             + (q4[3].z+eq4.z)*(kh3.z+tz) + (q4[3].w+eq4.w)*(kh3.w+tw);
        }
#pragma unroll
        for (int off = 1; off < 16; off <<= 1) {
          p0 += __shfl_xor(p0, off, 64);
          p1 += __shfl_xor(p1, off, 64);
          p2 += __shfl_xor(p2, off, 64);
          p3 += __shfl_xor(p3, off, 64);
        }
        if (i < n && ll < 4) {
          const float s = (ll == 0) ? p0 : (ll == 1) ? p1 : (ll == 2) ? p2 : p3;
          s_attn[ll][i] = s * SCALE_F;
        }
      }
      __syncthreads();

      {
        const float v0 = (l < n) ? s_attn[w][l] : -INFINITY;
        const float v1 = (64 + l < n) ? s_attn[w][64 + l] : -INFINITY;
        float mx = fmaxf(v0, v1);
#pragma unroll
        for (int off = 32; off; off >>= 1) mx = fmaxf(mx, __shfl_xor(mx, off, 64));
        const float e0 = (l < n) ? expf(v0 - mx) : 0.f;
        const float e1 = (64 + l < n) ? expf(v1 - mx) : 0.f;
        float sm = e0 + e1;
#pragma unroll
        for (int off = 32; off; off >>= 1) sm += __shfl_xor(sm, off, 64);
        const float inv = 1.0f / sm;
        if (l < n) s_attn[w][l] = e0 * inv;
        if (64 + l < n) s_attn[w][64 + l] = e1 * inv;
      }
    }
    __syncthreads();

    {
      const float* evb2 = evt + ((size_t)(b * S_LEN + q)) * S_LEN * DH;
      const float* vbp  = vp + (size_t)b * S_LEN * HDIM + w * DH + ll * 4;
      float ax = 0.f, ay = 0.f, az = 0.f, aw2 = 0.f;
      for (int i0 = 0; i0 < n; i0 += 4) {
        const int i = i0 + g;
        if (i < n) {
          const int kk = s_list[i];
          const float a = s_attn[w][i];
          const float4 v4 = *(const float4*)(vbp + (size_t)kk * HDIM);
          const float4 e4 = *(const float4*)(evb2 + kk * DH + ll * 4);
          ax  += a * (v4.x + e4.x);
          ay  += a * (v4.y + e4.y);
          az  += a * (v4.z + e4.z);
          aw2 += a * (v4.w + e4.w);
        }
      }
#pragma unroll
      for (int off = 16; off < 64; off <<= 1) {
        ax  += __shfl_xor(ax, off, 64);
        ay  += __shfl_xor(ay, off, 64);
        az  += __shfl_xor(az, off, 64);
        aw2 += __shfl_xor(aw2, off, 64);
      }
      if (g == 0) {
        bf16x4 rr;
        rr[0] = (__bf16)ax; rr[1] = (__bf16)ay;
        rr[2] = (__bf16)az; rr[3] = (__bf16)aw2;
        *(bf16x4*)(xpb + ((size_t)b * S_LEN + q) * HDIM + w * 64 + ll * 4) = rr;
      }
    }
  }
  grid_barrier(cnt + 32, NBLK);

  // ============ Phase 3: output projection (1016 tile-waves) ==============
  {
    const int gw = blockIdx.x * 4 + w;
    if (gw < 1016)
      gemm_tile32_bf16(xpb, Wob, bo, out, (gw % 127) * 32, (gw / 127) * 32);
  }
}

extern "C" void kernel_launch(void* const* d_in, const int* in_sizes, int n_in,
                              void* d_out, int out_size, void* d_ws, size_t ws_size,
                              hipStream_t stream) {
  const float* query = (const float*)d_in[0];
  const float* key   = (const float*)d_in[1];
  const float* value = (const float*)d_in[2];
  const int*   graph = (const int*)d_in[3];
  const float* ekt   = (const float*)d_in[4];
  const float* evt   = (const float*)d_in[5];
  const float* eqt   = (const float*)d_in[6];
  const float* Wq = (const float*)d_in[7];  const float* bq = (const float*)d_in[8];
  const float* Wk = (const float*)d_in[9];  const float* bk = (const float*)d_in[10];
  const float* Wv = (const float*)d_in[11]; const float* bv = (const float*)d_in[12];
  const float* Wo = (const float*)d_in[13]; const float* bo = (const float*)d_in[14];
  float* out = (float*)d_out;

  const size_t NE = (size_t)NTOK * HDIM;   // 1,040,384 elems
  unsigned* cnt = (unsigned*)d_ws;         // 3 counters, 64B apart
  char* p = (char*)d_ws + 256;
  float* qp = (float*)p;            p += NE * 4;
  float* kp = (float*)p;            p += NE * 4;
  float* vp = (float*)p;            p += NE * 4;
  __bf16* qb  = (__bf16*)p;         p += NE * 2;
  __bf16* kb  = (__bf16*)p;         p += NE * 2;
  __bf16* vb  = (__bf16*)p;         p += NE * 2;
  __bf16* xpb = (__bf16*)p;         p += NE * 2;
  __bf16* Wqb = (__bf16*)p;         p += (size_t)HDIM * HDIM * 2;
  __bf16* Wkb = (__bf16*)p;         p += (size_t)HDIM * HDIM * 2;
  __bf16* Wvb = (__bf16*)p;         p += (size_t)HDIM * HDIM * 2;
  __bf16* Wob = (__bf16*)p;

  hipMemsetAsync(cnt, 0, 256, stream);
  fused_mha<<<dim3(NBLK), NTHR, 0, stream>>>(
      query, key, value, graph, ekt, evt, eqt,
      Wq, bq, Wk, bk, Wv, bv, Wo, bo,
      qp, kp, vp, qb, kb, vb, xpb, Wqb, Wkb, Wvb, Wob,
      out, cnt);
}

// Round 8
// 51.994 us; speedup vs baseline: 12.9096x; 12.9096x over previous
//
#include <hip/hip_runtime.h>
#include <hip/hip_bf16.h>

#define S_LEN 127
#define NB    32
#define HDIM  256
#define DH    64
#define SCALE_F 0.125f

typedef __bf16 bf16x8 __attribute__((ext_vector_type(8)));
typedef __bf16 bf16x4 __attribute__((ext_vector_type(4)));
typedef float  f32x4  __attribute__((ext_vector_type(4)));

#define NTOK  4064                 // NB * S_LEN
#define NW4   16384                // 256*256/4 float4 groups per W

__device__ __forceinline__ float4 b2f4(bf16x4 v) {
  return make_float4((float)v[0], (float)v[1], (float)v[2], (float)v[3]);
}

// ---------------------------------------------------------------------------
// Tiny W-only f32 -> bf16 conversion (4 x 256x256). 256 blocks x 256 thr.
// ---------------------------------------------------------------------------
__global__ __launch_bounds__(256) void convert_w(
    const float* __restrict__ Wq, const float* __restrict__ Wk,
    const float* __restrict__ Wv, const float* __restrict__ Wo,
    __bf16* __restrict__ Wqb, __bf16* __restrict__ Wkb,
    __bf16* __restrict__ Wvb, __bf16* __restrict__ Wob)
{
  size_t t = (size_t)blockIdx.x * 256 + threadIdx.x;   // float4 index
  const float* src; __bf16* dst;
  if (t < NW4)                 { src = Wq; dst = Wqb; }
  else if ((t -= NW4) < NW4)   { src = Wk; dst = Wkb; }
  else if ((t -= NW4) < NW4)   { src = Wv; dst = Wvb; }
  else { t -= NW4;               src = Wo; dst = Wob; }
  const float4 x = ((const float4*)src)[t];
  bf16x4 r;
  r[0] = (__bf16)x.x; r[1] = (__bf16)x.y; r[2] = (__bf16)x.z; r[3] = (__bf16)x.w;
  ((bf16x4*)dst)[t] = r;
}

// ---------------------------------------------------------------------------
// q/k/v projection with in-LDS A conversion. One block per (row-tile, matrix):
// grid (127, 3), 256 threads. Block stages its 32x256 f32 A rows as bf16 in
// LDS (stride 264 elems: 16B-aligned rows, spread banks), then 4 waves each
// compute a 32x64 output strip (2 mi x 4 ni x 8 k-steps MFMA), W bf16 global
// with 1-step k-lookahead. Outputs written bf16 (consumed by attn / o-GEMM).
// ---------------------------------------------------------------------------
__global__ __launch_bounds__(256) void gemm_qkv(
    const float* __restrict__ q_in, const float* __restrict__ k_in,
    const float* __restrict__ v_in,
    const __bf16* __restrict__ Wqb, const float* __restrict__ bq,
    const __bf16* __restrict__ Wkb, const float* __restrict__ bk,
    const __bf16* __restrict__ Wvb, const float* __restrict__ bv,
    __bf16* __restrict__ qpb, __bf16* __restrict__ kpb, __bf16* __restrict__ vpb)
{
  const int tile = blockIdx.x;       // 0..126
  const float* A; const __bf16* W; const float* bias; __bf16* o;
  if (blockIdx.y == 0)      { A = q_in; W = Wqb; bias = bq; o = qpb; }
  else if (blockIdx.y == 1) { A = k_in; W = Wkb; bias = bk; o = kpb; }
  else                      { A = v_in; W = Wvb; bias = bv; o = vpb; }

  __shared__ __bf16 sA[32][264];
  const int row0 = tile * 32;

  // ---- stage A: 2048 float4s, 8 per thread, cvt f32->bf16 into LDS ----
#pragma unroll
  for (int j = 0; j < 8; ++j) {
    const int f = threadIdx.x + j * 256;   // 0..2047
    const int rr = f >> 6, c4 = f & 63;
    const float4 x = *(const float4*)(A + (size_t)(row0 + rr) * HDIM + c4 * 4);
    __bf16* d = &sA[rr][c4 * 4];
    d[0] = (__bf16)x.x; d[1] = (__bf16)x.y; d[2] = (__bf16)x.z; d[3] = (__bf16)x.w;
  }
  __syncthreads();

  const int w    = threadIdx.x >> 6;
  const int lane = threadIdx.x & 63;
  const int r    = lane & 15;
  const int ksl  = (lane >> 4) << 3;
  const int wc   = w * 64;                 // wave's 64-col strip

  const __bf16* Wb = W + (size_t)(wc + r) * HDIM + ksl;
  f32x4 acc[2][4] = {};

  bf16x8 cw[4];
#pragma unroll
  for (int ni = 0; ni < 4; ++ni)
    cw[ni] = *(const bf16x8*)(Wb + (size_t)ni * 16 * HDIM);
#pragma unroll
  for (int kb = 0; kb < 8; ++kb) {
    bf16x8 nw[4];
    if (kb < 7) {
#pragma unroll
      for (int ni = 0; ni < 4; ++ni)
        nw[ni] = *(const bf16x8*)(Wb + (size_t)ni * 16 * HDIM + (kb + 1) * 32);
    }
    const bf16x8 a0 = *(const bf16x8*)&sA[r][kb * 32 + ksl];
    const bf16x8 a1 = *(const bf16x8*)&sA[16 + r][kb * 32 + ksl];
#pragma unroll
    for (int ni = 0; ni < 4; ++ni) {
      acc[0][ni] = __builtin_amdgcn_mfma_f32_16x16x32_bf16(a0, cw[ni], acc[0][ni], 0, 0, 0);
      acc[1][ni] = __builtin_amdgcn_mfma_f32_16x16x32_bf16(a1, cw[ni], acc[1][ni], 0, 0, 0);
    }
    if (kb < 7) {
#pragma unroll
      for (int ni = 0; ni < 4; ++ni) cw[ni] = nw[ni];
    }
  }
  const int crow = (lane >> 4) * 4;
  const int ccol = lane & 15;
#pragma unroll
  for (int mi = 0; mi < 2; ++mi)
#pragma unroll
    for (int ni = 0; ni < 4; ++ni) {
      const int oc = wc + ni * 16 + ccol;
      const float bv = bias[oc];
#pragma unroll
      for (int rg = 0; rg < 4; ++rg)
        o[(size_t)(row0 + mi * 16 + crow + rg) * HDIM + oc] =
            (__bf16)(acc[mi][ni][rg] + bv);
    }
}

// ---------------------------------------------------------------------------
// Output projection: per-wave 32x32 tile, bf16 A (xpb) and W. R6-proven.
// ---------------------------------------------------------------------------
__global__ __launch_bounds__(256) void gemm_o(
    const __bf16* __restrict__ A, const __bf16* __restrict__ W,
    const float* __restrict__ bias, float* __restrict__ out)
{
  const int w = threadIdx.x >> 6;
  const int tile = blockIdx.x * 4 + w;
  if (tile >= 127) return;
  const int row0 = tile * 32, col0 = blockIdx.y * 32;
  const int lane = threadIdx.x & 63;
  const int r  = lane & 15;
  const int ks = (lane >> 4) << 3;
  const __bf16* Ab = A + (size_t)(row0 + r) * HDIM + ks;
  const __bf16* Wb = W + (size_t)(col0 + r) * HDIM + ks;
  f32x4 acc[2][2] = {};

  bf16x8 ca[2], cw[2];
  ca[0] = *(const bf16x8*)Ab;
  ca[1] = *(const bf16x8*)(Ab + (size_t)16 * HDIM);
  cw[0] = *(const bf16x8*)Wb;
  cw[1] = *(const bf16x8*)(Wb + (size_t)16 * HDIM);
#pragma unroll
  for (int kb = 0; kb < 8; ++kb) {
    bf16x8 na[2], nw[2];
    if (kb < 7) {
      const int off = (kb + 1) * 32;
      na[0] = *(const bf16x8*)(Ab + off);
      na[1] = *(const bf16x8*)(Ab + (size_t)16 * HDIM + off);
      nw[0] = *(const bf16x8*)(Wb + off);
      nw[1] = *(const bf16x8*)(Wb + (size_t)16 * HDIM + off);
    }
#pragma unroll
    for (int mi = 0; mi < 2; ++mi)
#pragma unroll
      for (int ni = 0; ni < 2; ++ni)
        acc[mi][ni] = __builtin_amdgcn_mfma_f32_16x16x32_bf16(
            ca[mi], cw[ni], acc[mi][ni], 0, 0, 0);
    if (kb < 7) {
      ca[0] = na[0]; ca[1] = na[1];
      cw[0] = nw[0]; cw[1] = nw[1];
    }
  }
  const int crow = (lane >> 4) * 4;
  const int ccol = lane & 15;
#pragma unroll
  for (int mi = 0; mi < 2; ++mi)
#pragma unroll
    for (int ni = 0; ni < 2; ++ni) {
      const int oc = col0 + ni * 16 + ccol;
      const float bv = bias[oc];
#pragma unroll
      for (int rg = 0; rg < 4; ++rg)
        out[(size_t)(row0 + mi * 16 + crow + rg) * HDIM + oc] = acc[mi][ni][rg] + bv;
    }
}

// ---------------------------------------------------------------------------
// Fused sparse attention. bf16 q/k/v, f32 edge tensors. 16-lane-group-per-
// column layout with 1-step prefetch in score and PV loops. Long-pole items
// (q<3, n~63) on the first 96 blocks.
// ---------------------------------------------------------------------------
__global__ __launch_bounds__(256) void attn_kernel(
    const __bf16* __restrict__ qpb, const __bf16* __restrict__ kpb,
    const __bf16* __restrict__ vpb, const int* __restrict__ graph,
    const float* __restrict__ ekt, const float* __restrict__ evt,
    const float* __restrict__ eqt, __bf16* __restrict__ xpb)
{
  int b, q;
  {
    const int bx = blockIdx.x;
    if (bx < 96) { b = bx / 3; q = bx % 3; }
    else { const int rr = bx - 96; b = rr / 124; q = 3 + rr % 124; }
  }
  const int t = threadIdx.x;
  const int w = t >> 6;        // wave 0..3
  const int l = t & 63;        // lane
  const int ll = l & 15;       // d-group: d = ll*4 .. ll*4+3
  const int g  = l >> 4;       // column slot 0..3

  __shared__ int   s_list[S_LEN];
  __shared__ float s_attn[4][S_LEN];
  __shared__ int   s_cnt[2];

  // ---- compacted valid-k list ----
  bool valid = false;
  const int k0 = w * 64 + l;
  if (w < 2 && k0 < S_LEN) {
    const int gr = graph[((size_t)b * S_LEN + q) * S_LEN + k0];
    bool keep;
    if (q < 3 || k0 < 3) keep = true;
    else {
      const int blk = 3 + 2 * ((q - 3) >> 1);
      keep = (k0 >= blk) & (k0 < blk + 2);
    }
    valid = (gr != 0) && keep;
  }
  const unsigned long long bal = __ballot(valid);
  if (w < 2 && l == 0) s_cnt[w] = (int)__popcll(bal);
  __syncthreads();
  int n = s_cnt[0] + s_cnt[1];
  if (valid) {
    const int pos = (int)__popcll(bal & ((1ull << l) - 1ull)) + (w ? s_cnt[0] : 0);
    s_list[pos] = k0;
  }
  __syncthreads();

  if (n == 0) {
    if (t < S_LEN) {
      s_list[t] = t;
      const float u = 1.0f / 127.0f;
      s_attn[0][t] = u; s_attn[1][t] = u; s_attn[2][t] = u; s_attn[3][t] = u;
    }
    n = S_LEN;
  } else {
    // ---- scores: group (w,g) owns column i0 + w*4 + g, prefetched ----
    const __bf16* qrow = qpb + ((size_t)b * S_LEN + q) * HDIM;
    float4 q4[4];
#pragma unroll
    for (int h = 0; h < 4; ++h)
      q4[h] = b2f4(*(const bf16x4*)(qrow + h * 64 + ll * 4));
    const float* eqb2 = eqt + ((size_t)b * S_LEN * S_LEN + q) * DH;
    const float* ekb2 = ekt + ((size_t)(b * S_LEN + q)) * S_LEN * DH;
    const __bf16* kpbb = kpb + (size_t)b * S_LEN * HDIM;
    const int myi = w * 4 + g;

    float4 ceq, cek;
    bf16x4 ck0, ck1, ck2, ck3;
    if (myi < n) {
      const int kk = s_list[myi];
      ceq = *(const float4*)(eqb2 + (size_t)kk * (S_LEN * DH) + ll * 4);
      cek = *(const float4*)(ekb2 + kk * DH + ll * 4);
      const __bf16* kr = kpbb + (size_t)kk * HDIM + ll * 4;
      ck0 = *(const bf16x4*)(kr);
      ck1 = *(const bf16x4*)(kr + 64);
      ck2 = *(const bf16x4*)(kr + 128);
      ck3 = *(const bf16x4*)(kr + 192);
    }
    for (int i0 = 0; i0 < n; i0 += 16) {
      const int i = i0 + myi;
      float4 neq, nek;
      bf16x4 nk0, nk1, nk2, nk3;
      const int j = i + 16;
      if (j < n) {
        const int kk = s_list[j];
        neq = *(const float4*)(eqb2 + (size_t)kk * (S_LEN * DH) + ll * 4);
        nek = *(const float4*)(ekb2 + kk * DH + ll * 4);
        const __bf16* kr = kpbb + (size_t)kk * HDIM + ll * 4;
        nk0 = *(const bf16x4*)(kr);
        nk1 = *(const bf16x4*)(kr + 64);
        nk2 = *(const bf16x4*)(kr + 128);
        nk3 = *(const bf16x4*)(kr + 192);
      }
      float p0 = 0.f, p1 = 0.f, p2 = 0.f, p3 = 0.f;
      if (i < n) {
        const float4 k0f = b2f4(ck0), k1f = b2f4(ck1),
                     k2f = b2f4(ck2), k3f = b2f4(ck3);
        p0 = (q4[0].x+ceq.x)*(k0f.x+cek.x) + (q4[0].y+ceq.y)*(k0f.y+cek.y)
           + (q4[0].z+ceq.z)*(k0f.z+cek.z) + (q4[0].w+ceq.w)*(k0f.w+cek.w);
        p1 = (q4[1].x+ceq.x)*(k1f.x+cek.x) + (q4[1].y+ceq.y)*(k1f.y+cek.y)
           + (q4[1].z+ceq.z)*(k1f.z+cek.z) + (q4[1].w+ceq.w)*(k1f.w+cek.w);
        p2 = (q4[2].x+ceq.x)*(k2f.x+cek.x) + (q4[2].y+ceq.y)*(k2f.y+cek.y)
           + (q4[2].z+ceq.z)*(k2f.z+cek.z) + (q4[2].w+ceq.w)*(k2f.w+cek.w);
        p3 = (q4[3].x+ceq.x)*(k3f.x+cek.x) + (q4[3].y+ceq.y)*(k3f.y+cek.y)
           + (q4[3].z+ceq.z)*(k3f.z+cek.z) + (q4[3].w+ceq.w)*(k3f.w+cek.w);
      }
#pragma unroll
      for (int off = 1; off < 16; off <<= 1) {
        p0 += __shfl_xor(p0, off, 64);
        p1 += __shfl_xor(p1, off, 64);
        p2 += __shfl_xor(p2, off, 64);
        p3 += __shfl_xor(p3, off, 64);
      }
      if (i < n && ll < 4) {
        const float s = (ll == 0) ? p0 : (ll == 1) ? p1 : (ll == 2) ? p2 : p3;
        s_attn[ll][i] = s * SCALE_F;
      }
      ceq = neq; cek = nek;
      ck0 = nk0; ck1 = nk1; ck2 = nk2; ck3 = nk3;
    }
    __syncthreads();

    // ---- softmax per head ----
    {
      const float v0 = (l < n) ? s_attn[w][l] : -INFINITY;
      const float v1 = (64 + l < n) ? s_attn[w][64 + l] : -INFINITY;
      float mx = fmaxf(v0, v1);
#pragma unroll
      for (int off = 32; off; off >>= 1) mx = fmaxf(mx, __shfl_xor(mx, off, 64));
      const float e0 = (l < n) ? expf(v0 - mx) : 0.f;
      const float e1 = (64 + l < n) ? expf(v1 - mx) : 0.f;
      float sm = e0 + e1;
#pragma unroll
      for (int off = 32; off; off >>= 1) sm += __shfl_xor(sm, off, 64);
      const float inv = 1.0f / sm;
      if (l < n) s_attn[w][l] = e0 * inv;
      if (64 + l < n) s_attn[w][64 + l] = e1 * inv;
    }
  }
  __syncthreads();

  // ---- PV: wave w = head w; group g handles columns g, g+4, ...; prefetched ----
  {
    const float* evb2 = evt + ((size_t)(b * S_LEN + q)) * S_LEN * DH;
    const __bf16* vbp = vpb + (size_t)b * S_LEN * HDIM + w * DH + ll * 4;
    float ax = 0.f, ay = 0.f, az = 0.f, aw2 = 0.f;

    int i = g;
    float a = 0.f; bf16x4 v4; float4 e4;
    if (i < n) {
      const int kk = s_list[i];
      a = s_attn[w][i];
      v4 = *(const bf16x4*)(vbp + (size_t)kk * HDIM);
      e4 = *(const float4*)(evb2 + kk * DH + ll * 4);
    }
    while (i < n) {
      const int j = i + 4;
      float a2 = 0.f; bf16x4 v42; float4 e42;
      if (j < n) {
        const int kk = s_list[j];
        a2 = s_attn[w][j];
        v42 = *(const bf16x4*)(vbp + (size_t)kk * HDIM);
        e42 = *(const float4*)(evb2 + kk * DH + ll * 4);
      }
      const float4 vf = b2f4(v4);
      ax  += a * (vf.x + e4.x);
      ay  += a * (vf.y + e4.y);
      az  += a * (vf.z + e4.z);
      aw2 += a * (vf.w + e4.w);
      i = j; a = a2; v4 = v42; e4 = e42;
    }
#pragma unroll
    for (int off = 16; off < 64; off <<= 1) {
      ax  += __shfl_xor(ax, off, 64);
      ay  += __shfl_xor(ay, off, 64);
      az  += __shfl_xor(az, off, 64);
      aw2 += __shfl_xor(aw2, off, 64);
    }
    if (g == 0) {
      bf16x4 rr;
      rr[0] = (__bf16)ax; rr[1] = (__bf16)ay;
      rr[2] = (__bf16)az; rr[3] = (__bf16)aw2;
      *(bf16x4*)(xpb + ((size_t)b * S_LEN + q) * HDIM + w * 64 + ll * 4) = rr;
    }
  }
}

extern "C" void kernel_launch(void* const* d_in, const int* in_sizes, int n_in,
                              void* d_out, int out_size, void* d_ws, size_t ws_size,
                              hipStream_t stream) {
  const float* query = (const float*)d_in[0];
  const float* key   = (const float*)d_in[1];
  const float* value = (const float*)d_in[2];
  const int*   graph = (const int*)d_in[3];
  const float* ekt   = (const float*)d_in[4];
  const float* evt   = (const float*)d_in[5];
  const float* eqt   = (const float*)d_in[6];
  const float* Wq = (const float*)d_in[7];  const float* bq = (const float*)d_in[8];
  const float* Wk = (const float*)d_in[9];  const float* bk = (const float*)d_in[10];
  const float* Wv = (const float*)d_in[11]; const float* bv = (const float*)d_in[12];
  const float* Wo = (const float*)d_in[13]; const float* bo = (const float*)d_in[14];
  float* out = (float*)d_out;

  const size_t NE = (size_t)NTOK * HDIM;   // 1,040,384 elems
  char* p = (char*)d_ws;
  __bf16* qpb = (__bf16*)p;         p += NE * 2;
  __bf16* kpb = (__bf16*)p;         p += NE * 2;
  __bf16* vpb = (__bf16*)p;         p += NE * 2;
  __bf16* xpb = (__bf16*)p;         p += NE * 2;
  __bf16* Wqb = (__bf16*)p;         p += (size_t)HDIM * HDIM * 2;
  __bf16* Wkb = (__bf16*)p;         p += (size_t)HDIM * HDIM * 2;
  __bf16* Wvb = (__bf16*)p;         p += (size_t)HDIM * HDIM * 2;
  __bf16* Wob = (__bf16*)p;

  convert_w<<<dim3(256), 256, 0, stream>>>(Wq, Wk, Wv, Wo, Wqb, Wkb, Wvb, Wob);
  gemm_qkv<<<dim3(127, 3), 256, 0, stream>>>(query, key, value,
                                             Wqb, bq, Wkb, bk, Wvb, bv,
                                             qpb, kpb, vpb);
  attn_kernel<<<dim3(NB * S_LEN), 256, 0, stream>>>(qpb, kpb, vpb, graph,
                                                    ekt, evt, eqt, xpb);
  gemm_o<<<dim3(32, 8), 256, 0, stream>>>(xpb, Wob, bo, out);
}